// Round 2
// baseline (220.763 us; speedup 1.0000x reference)
//
#include <hip/hip_runtime.h>
#include <hip/hip_bf16.h>

typedef unsigned short u16;
typedef unsigned int   u32;
typedef unsigned long long u64;

#define BATCH 4096
#define IDIM  1024
#define ODIM  1024
#define NDEG  9                 // degree 8 -> 9 basis terms
#define KTOT  (IDIM * NDEG)     // 9216

#define BM 128
#define BN 128
#define BKK 64

typedef __attribute__((ext_vector_type(8))) short short8_t;   // 8 bf16 = 4 VGPRs
typedef __attribute__((ext_vector_type(4))) float f32x4;

// round-to-nearest-even f32 -> bf16 (values are finite; no NaN handling needed)
__device__ __forceinline__ u16 f2bf(float f) {
    union { float f; u32 u; } v; v.f = f;
    u32 r = v.u + 0x7FFFu + ((v.u >> 16) & 1u);
    return (u16)(r >> 16);
}
__device__ __forceinline__ u32 pack2bf(float lo, float hi) {
    return (u32)f2bf(lo) | ((u32)f2bf(hi) << 16);
}

// async 16B global -> LDS (hardware: wave-uniform base + lane*16)
__device__ __forceinline__ void gl_lds16(const u16* g, u16* l) {
    __builtin_amdgcn_global_load_lds(
        (const __attribute__((address_space(1))) void*)g,
        (__attribute__((address_space(3))) void*)l,
        16, 0, 0);
}

// ---------------------------------------------------------------------------
// A[b][k] bf16, k = d*1024 + i :  A = V_d(tanh(x[b,i]))
// thread handles 2 consecutive i -> packed u32 stores (coalesced per d)
// ---------------------------------------------------------------------------
__global__ void prep_a_kernel(const float* __restrict__ x, u16* __restrict__ A) {
    int t  = blockIdx.x * 256 + threadIdx.x;      // over BATCH*IDIM/2
    int b  = t >> 9;
    int i2 = (t & 511) << 1;
    float2 xv = ((const float2*)x)[t];
    float t0 = tanhf(xv.x), t1 = tanhf(xv.y);
    u32* dst = (u32*)(A + (size_t)b * KTOT + i2); // d-stride = 1024 u16 = 512 u32
    float a0 = 2.0f, a1 = 2.0f;                   // V0
    float b0 = t0,  b1 = t1;                      // V1
    dst[0]   = pack2bf(2.0f, 2.0f);
    dst[512] = pack2bf(t0, t1);
#pragma unroll
    for (int d = 2; d < NDEG; ++d) {
        float n0 = t0 * b0 + a0;
        float n1 = t1 * b1 + a1;
        dst[(size_t)d * 512] = pack2bf(n0, n1);
        a0 = b0; b0 = n0; a1 = b1; b1 = n1;
    }
}

// ---------------------------------------------------------------------------
// Bt[o][k] bf16, k = d*1024 + i  from coeffs[i][o][d] (d fastest).
// Tiled transpose via LDS: block = 128 i x 8 o x 9 d.
//   read : runs of 72 contiguous floats per i  -> coalesced dword loads
//   LDS  : [j = o*9+d][ii] u16, stride 132 (u64-aligned write-out rows)
//   write: 4 consecutive i per lane as one u64 -> 512 B per wave store
// ---------------------------------------------------------------------------
#define PB_TI 128
#define PB_TO 8
#define PB_J  (PB_TO * NDEG)    // 72
#define PB_LS 132               // LDS row stride (u16), 264 B: 8B-aligned rows

__global__ void prep_b_kernel(const float* __restrict__ c, u16* __restrict__ Bt) {
    __shared__ u16 lds[PB_J * PB_LS];             // 19 KB
    const int tid = threadIdx.x;
    const int i0  = blockIdx.y * PB_TI;
    const int o0  = blockIdx.x * PB_TO;
    const float* src = c + (size_t)i0 * (ODIM * NDEG) + (size_t)o0 * NDEG;

#pragma unroll
    for (int t = 0; t < 36; ++t) {                // 9216 floats / 256 threads
        int f  = t * 256 + tid;
        int ii = f / PB_J;
        int j  = f - ii * PB_J;
        float v = src[(size_t)ii * (ODIM * NDEG) + j];
        lds[j * PB_LS + ii] = f2bf(v);
    }
    __syncthreads();

#pragma unroll
    for (int t = 0; t < 9; ++t) {                 // 72*32 u64 stores / 256 thr
        int g   = t * 256 + tid;                  // 0..2303
        int j   = g >> 5;                         // 0..71
        int ii4 = (g & 31) << 2;                  // 0,4,..,124
        int o   = j / NDEG;
        int d   = j - o * NDEG;
        u64 v = *(const u64*)(lds + j * PB_LS + ii4);
        *(u64*)(Bt + (size_t)(o0 + o) * KTOT + d * 1024 + i0 + ii4) = v;
    }
}

// ---------------------------------------------------------------------------
// GEMM: C[m][n] += A[m][k] * Bt[n][k], 128x128 tile, BK=64, 4 waves of 64x64.
// LDS layout: tile as [row][8 chunks of 16B], physical chunk = c ^ (row&7)
// -> global_load_lds staging + conflict-free ds_read_b128 frag reads.
// Split-K over blockIdx.z for occupancy (4 blocks/CU).
// ---------------------------------------------------------------------------
__global__ __launch_bounds__(256, 4)
void gemm_kernel(const u16* __restrict__ A, const u16* __restrict__ B,
                 float* __restrict__ C, int kLen) {
    __shared__ __align__(16) u16 ldsA[BM * BKK];  // 16 KB
    __shared__ __align__(16) u16 ldsB[BN * BKK];  // 16 KB

    const int tid  = threadIdx.x;
    const int lane = tid & 63;
    const int wave = tid >> 6;
    const int quad = lane >> 4;
    const int l15  = lane & 15;
    const int wm   = wave & 1;
    const int wn   = wave >> 1;
    const int bm   = blockIdx.y;
    const int bn   = blockIdx.x;
    const int kStart = blockIdx.z * kLen;
    C += (size_t)blockIdx.z * BATCH * ODIM;

    const u16* ga[4]; const u16* gb[4];
    u16* la[4]; u16* lb[4];
#pragma unroll
    for (int t = 0; t < 4; ++t) {
        int s  = t * 256 + tid;                   // 16B slot in tile, 0..1023
        int r  = s >> 3;                          // tile row 0..127
        int sc = (s & 7) ^ (r & 7);               // source k-chunk (XOR swizzle)
        ga[t] = A + (size_t)(bm * BM + r) * KTOT + kStart + sc * 8;
        gb[t] = B + (size_t)(bn * BN + r) * KTOT + kStart + sc * 8;
        la[t] = ldsA + s * 8;
        lb[t] = ldsB + s * 8;
    }

    f32x4 acc[4][4];
#pragma unroll
    for (int mt = 0; mt < 4; ++mt)
#pragma unroll
        for (int nt = 0; nt < 4; ++nt)
            acc[mt][nt] = (f32x4){0.f, 0.f, 0.f, 0.f};

    const int nIter = kLen / BKK;
    for (int it = 0; it < nIter; ++it) {
#pragma unroll
        for (int t = 0; t < 4; ++t) gl_lds16(ga[t], la[t]);
#pragma unroll
        for (int t = 0; t < 4; ++t) gl_lds16(gb[t], lb[t]);
        __syncthreads();

#pragma unroll
        for (int kk = 0; kk < 2; ++kk) {
            short8_t af[4], bfg[4];
#pragma unroll
            for (int mt = 0; mt < 4; ++mt) {
                int row = wm * 64 + mt * 16 + l15;
                int pc  = (kk * 4 + quad) ^ (row & 7);
                af[mt] = *(const short8_t*)(ldsA + (row * 8 + pc) * 8);
            }
#pragma unroll
            for (int nt = 0; nt < 4; ++nt) {
                int row = wn * 64 + nt * 16 + l15;
                int pc  = (kk * 4 + quad) ^ (row & 7);
                bfg[nt] = *(const short8_t*)(ldsB + (row * 8 + pc) * 8);
            }
#pragma unroll
            for (int mt = 0; mt < 4; ++mt)
#pragma unroll
                for (int nt = 0; nt < 4; ++nt)
                    acc[mt][nt] = __builtin_amdgcn_mfma_f32_16x16x32_bf16(
                        af[mt], bfg[nt], acc[mt][nt], 0, 0, 0);
        }
        __syncthreads();

#pragma unroll
        for (int t = 0; t < 4; ++t) { ga[t] += BKK; gb[t] += BKK; }
    }

    // epilogue: C/D layout col = lane&15, row = quad*4 + reg  [m89-verified]
#pragma unroll
    for (int mt = 0; mt < 4; ++mt) {
#pragma unroll
        for (int nt = 0; nt < 4; ++nt) {
            int row0 = bm * BM + wm * 64 + mt * 16 + quad * 4;
            int col  = bn * BN + wn * 64 + nt * 16 + l15;
#pragma unroll
            for (int r = 0; r < 4; ++r)
                C[(size_t)(row0 + r) * ODIM + col] = acc[mt][nt][r];
        }
    }
}

// out = sum_s P[s]  (split-K reduction), float4 vectorized
__global__ void reduce_kernel(const float* __restrict__ P, float* __restrict__ out,
                              int S) {
    int t = blockIdx.x * 256 + threadIdx.x;       // over BATCH*ODIM/4
    f32x4 a = ((const f32x4*)P)[t];
    for (int s = 1; s < S; ++s)
        a += ((const f32x4*)(P + (size_t)s * BATCH * ODIM))[t];
    ((f32x4*)out)[t] = a;
}

extern "C" void kernel_launch(void* const* d_in, const int* in_sizes, int n_in,
                              void* d_out, int out_size, void* d_ws, size_t ws_size,
                              hipStream_t stream) {
    const float* x      = (const float*)d_in[0];   // [4096,1024] f32
    const float* coeffs = (const float*)d_in[1];   // [1024,1024,9] f32
    float* out = (float*)d_out;                    // [4096,1024] f32

    u16* A  = (u16*)d_ws;                          // 75.5 MB
    u16* Bt = A + (size_t)BATCH * KTOT;            // 18.9 MB
    float* P = (float*)(Bt + (size_t)ODIM * KTOT); // split-K partials

    size_t need_base = ((size_t)BATCH * KTOT + (size_t)ODIM * KTOT) * 2;
    size_t per_part  = (size_t)BATCH * ODIM * 4;

    prep_a_kernel<<<BATCH * IDIM / 512, 256, 0, stream>>>(x, A);
    {
        dim3 g(ODIM / PB_TO, IDIM / PB_TI);        // 128 x 8
        prep_b_kernel<<<g, 256, 0, stream>>>(coeffs, Bt);
    }

    int S = 1;
    if (ws_size >= need_base + 4 * per_part) S = 4;        // 1024 blocks, 4/CU
    else if (ws_size >= need_base + 2 * per_part) S = 2;

    if (S > 1) {
        dim3 grid(ODIM / BN, BATCH / BM, S);
        gemm_kernel<<<grid, 256, 0, stream>>>(A, Bt, P, KTOT / S);
        reduce_kernel<<<BATCH * ODIM / 1024, 256, 0, stream>>>(P, out, S);
    } else {
        dim3 grid(ODIM / BN, BATCH / BM, 1);
        gemm_kernel<<<grid, 256, 0, stream>>>(A, Bt, out, KTOT);
    }
}

// Round 3
// 216.422 us; speedup vs baseline: 1.0201x; 1.0201x over previous
//
#include <hip/hip_runtime.h>
#include <hip/hip_bf16.h>

typedef unsigned short u16;
typedef unsigned int   u32;
typedef unsigned long long u64;

#define BATCH 4096
#define IDIM  1024
#define ODIM  1024
#define NDEG  9                 // degree 8 -> 9 basis terms
#define KTOT  (IDIM * NDEG)     // 9216

#define BM 128
#define BN 128
#define BKK 64

typedef __attribute__((ext_vector_type(8))) short short8_t;   // 8 bf16 = 4 VGPRs
typedef __attribute__((ext_vector_type(4))) float f32x4;

// round-to-nearest-even f32 -> bf16 (values are finite; no NaN handling needed)
__device__ __forceinline__ u16 f2bf(float f) {
    union { float f; u32 u; } v; v.f = f;
    u32 r = v.u + 0x7FFFu + ((v.u >> 16) & 1u);
    return (u16)(r >> 16);
}
__device__ __forceinline__ u32 pack2bf(float lo, float hi) {
    return (u32)f2bf(lo) | ((u32)f2bf(hi) << 16);
}

// async 16B global -> LDS (hardware: wave-uniform base + lane*16)
__device__ __forceinline__ void gl_lds16(const u16* g, u16* l) {
    __builtin_amdgcn_global_load_lds(
        (const __attribute__((address_space(1))) void*)g,
        (__attribute__((address_space(3))) void*)l,
        16, 0, 0);
}

// ---------------------------------------------------------------------------
// Fused prep (single dispatch, block-role split):
//   blocks [0, 1024)        : Bt[o][k=d*1024+i] <- coeffs[i][o][d] (LDS transpose)
//   blocks [1024, 9216)     : A[b][k=d*1024+i]  <- V_d(tanh(x[b,i]))
//   blocks [9216, 9472)     : out <- 0  (atomic-accumulate target for GEMM)
// ---------------------------------------------------------------------------
#define PB_TI 128
#define PB_TO 8
#define PB_J  (PB_TO * NDEG)    // 72
#define PB_LS 132               // LDS row stride (u16): 264 B, u64-aligned rows

#define NB_B   1024             // (IDIM/PB_TI) * (ODIM/PB_TO) = 8 * 128
#define NB_A   8192             // BATCH*IDIM/2 / 256
#define NB_Z   256

__global__ void prep_kernel(const float* __restrict__ x,
                            const float* __restrict__ c,
                            u16* __restrict__ A, u16* __restrict__ Bt,
                            float* __restrict__ out) {
    __shared__ u16 lds[PB_J * PB_LS];             // 19 KB (B-blocks only)
    const int bb  = blockIdx.x;
    const int tid = threadIdx.x;

    if (bb < NB_B) {
        // ---- B transpose: 128 i x 8 o x 9 d tile ----
        const int i0 = (bb & 7) * PB_TI;
        const int o0 = (bb >> 3) * PB_TO;
        const float* src = c + (size_t)i0 * (ODIM * NDEG) + (size_t)o0 * NDEG;
#pragma unroll
        for (int t = 0; t < 36; ++t) {            // 9216 floats / 256 threads
            int f  = t * 256 + tid;
            int ii = f / PB_J;
            int j  = f - ii * PB_J;
            float v = src[(size_t)ii * (ODIM * NDEG) + j];
            lds[j * PB_LS + ii] = f2bf(v);
        }
        __syncthreads();
#pragma unroll
        for (int t = 0; t < 9; ++t) {             // 72*32 u64 stores / 256 thr
            int g   = t * 256 + tid;
            int j   = g >> 5;                     // 0..71
            int ii4 = (g & 31) << 2;
            int o   = j / NDEG;
            int d   = j - o * NDEG;
            u64 v = *(const u64*)(lds + j * PB_LS + ii4);
            *(u64*)(Bt + (size_t)(o0 + o) * KTOT + d * 1024 + i0 + ii4) = v;
        }
    } else if (bb < NB_B + NB_A) {
        // ---- A basis: thread handles 2 consecutive i ----
        int t  = (bb - NB_B) * 256 + tid;
        int b  = t >> 9;
        int i2 = (t & 511) << 1;
        float2 xv = ((const float2*)x)[t];
        float t0 = tanhf(xv.x), t1 = tanhf(xv.y);
        u32* dst = (u32*)(A + (size_t)b * KTOT + i2);  // d-stride = 512 u32
        float a0 = 2.0f, a1 = 2.0f;
        float b0 = t0,  b1 = t1;
        dst[0]   = pack2bf(2.0f, 2.0f);
        dst[512] = pack2bf(t0, t1);
#pragma unroll
        for (int d = 2; d < NDEG; ++d) {
            float n0 = t0 * b0 + a0;
            float n1 = t1 * b1 + a1;
            dst[(size_t)d * 512] = pack2bf(n0, n1);
            a0 = b0; b0 = n0; a1 = b1; b1 = n1;
        }
    } else {
        // ---- zero d_out (16.8 MB) for atomic accumulation ----
        int t = (bb - NB_B - NB_A) * 256 + tid;   // 0..65535
        f32x4 z = (f32x4){0.f, 0.f, 0.f, 0.f};
#pragma unroll
        for (int r = 0; r < 16; ++r)
            ((f32x4*)out)[(size_t)r * (NB_Z * 256) + t] = z;
    }
}

// ---------------------------------------------------------------------------
// GEMM: out[m][n] (+)= A[m][k] * Bt[n][k], 128x128 tile, BK=64, 4 waves 64x64.
// LDS: tile as [row][8 chunks of 16B], physical chunk = c ^ (row&7)
// -> global_load_lds staging + conflict-free ds_read_b128 frag reads.
// Split-K=2 over blockIdx.z (512 blocks = 2/CU); epilogue atomicAdd into
// pre-zeroed out (fire-and-forget, 2-way contention max).
// ---------------------------------------------------------------------------
__global__ __launch_bounds__(256, 2)
void gemm_kernel(const u16* __restrict__ A, const u16* __restrict__ B,
                 float* __restrict__ C, int kLen) {
    __shared__ __align__(16) u16 ldsA[BM * BKK];  // 16 KB
    __shared__ __align__(16) u16 ldsB[BN * BKK];  // 16 KB

    const int tid  = threadIdx.x;
    const int lane = tid & 63;
    const int wave = tid >> 6;
    const int quad = lane >> 4;
    const int l15  = lane & 15;
    const int wm   = wave & 1;
    const int wn   = wave >> 1;
    const int bm   = blockIdx.y;
    const int bn   = blockIdx.x;
    const int kStart = blockIdx.z * kLen;

    const u16* ga[4]; const u16* gb[4];
    u16* la[4]; u16* lb[4];
#pragma unroll
    for (int t = 0; t < 4; ++t) {
        int s  = t * 256 + tid;                   // 16B slot in tile, 0..1023
        int r  = s >> 3;                          // tile row 0..127
        int sc = (s & 7) ^ (r & 7);               // source k-chunk (XOR swizzle)
        ga[t] = A + (size_t)(bm * BM + r) * KTOT + kStart + sc * 8;
        gb[t] = B + (size_t)(bn * BN + r) * KTOT + kStart + sc * 8;
        la[t] = ldsA + s * 8;
        lb[t] = ldsB + s * 8;
    }

    f32x4 acc[4][4];
#pragma unroll
    for (int mt = 0; mt < 4; ++mt)
#pragma unroll
        for (int nt = 0; nt < 4; ++nt)
            acc[mt][nt] = (f32x4){0.f, 0.f, 0.f, 0.f};

    const int nIter = kLen / BKK;
    for (int it = 0; it < nIter; ++it) {
#pragma unroll
        for (int t = 0; t < 4; ++t) gl_lds16(ga[t], la[t]);
#pragma unroll
        for (int t = 0; t < 4; ++t) gl_lds16(gb[t], lb[t]);
        __syncthreads();

#pragma unroll
        for (int kk = 0; kk < 2; ++kk) {
            short8_t af[4], bfg[4];
#pragma unroll
            for (int mt = 0; mt < 4; ++mt) {
                int row = wm * 64 + mt * 16 + l15;
                int pc  = (kk * 4 + quad) ^ (row & 7);
                af[mt] = *(const short8_t*)(ldsA + (row * 8 + pc) * 8);
            }
#pragma unroll
            for (int nt = 0; nt < 4; ++nt) {
                int row = wn * 64 + nt * 16 + l15;
                int pc  = (kk * 4 + quad) ^ (row & 7);
                bfg[nt] = *(const short8_t*)(ldsB + (row * 8 + pc) * 8);
            }
#pragma unroll
            for (int mt = 0; mt < 4; ++mt)
#pragma unroll
                for (int nt = 0; nt < 4; ++nt)
                    acc[mt][nt] = __builtin_amdgcn_mfma_f32_16x16x32_bf16(
                        af[mt], bfg[nt], acc[mt][nt], 0, 0, 0);
        }
        __syncthreads();

#pragma unroll
        for (int t = 0; t < 4; ++t) { ga[t] += BKK; gb[t] += BKK; }
    }

    // epilogue: C/D layout col = lane&15, row = quad*4 + reg  [m89-verified]
    // atomicAdd (no return use -> fire-and-forget global_atomic_add_f32)
#pragma unroll
    for (int mt = 0; mt < 4; ++mt) {
#pragma unroll
        for (int nt = 0; nt < 4; ++nt) {
            int row0 = bm * BM + wm * 64 + mt * 16 + quad * 4;
            int col  = bn * BN + wn * 64 + nt * 16 + l15;
#pragma unroll
            for (int r = 0; r < 4; ++r)
                atomicAdd(&C[(size_t)(row0 + r) * ODIM + col], acc[mt][nt][r]);
        }
    }
}

extern "C" void kernel_launch(void* const* d_in, const int* in_sizes, int n_in,
                              void* d_out, int out_size, void* d_ws, size_t ws_size,
                              hipStream_t stream) {
    const float* x      = (const float*)d_in[0];   // [4096,1024] f32
    const float* coeffs = (const float*)d_in[1];   // [1024,1024,9] f32
    float* out = (float*)d_out;                    // [4096,1024] f32

    u16* A  = (u16*)d_ws;                          // 75.5 MB
    u16* Bt = A + (size_t)BATCH * KTOT;            // 18.9 MB

    prep_kernel<<<NB_B + NB_A + NB_Z, 256, 0, stream>>>(x, coeffs, A, Bt, out);

    dim3 grid(ODIM / BN, BATCH / BM, 2);           // split-K=2: 512 blocks
    gemm_kernel<<<grid, 256, 0, stream>>>(A, Bt, out, KTOT / 2);
}

// Round 4
// 187.344 us; speedup vs baseline: 1.1784x; 1.1552x over previous
//
#include <hip/hip_runtime.h>
#include <hip/hip_bf16.h>

typedef unsigned short u16;
typedef unsigned int   u32;
typedef unsigned long long u64;

#define BATCH 4096
#define IDIM  1024
#define ODIM  1024
#define NDEG  9                 // degree 8 -> 9 basis terms
#define KTOT  (IDIM * NDEG)     // 9216

#define BM 128
#define BN 128
#define BKK 64

typedef __attribute__((ext_vector_type(8))) short short8_t;   // 8 bf16 = 4 VGPRs
typedef __attribute__((ext_vector_type(4))) float f32x4;

// round-to-nearest-even f32 -> bf16 (values are finite; no NaN handling needed)
__device__ __forceinline__ u16 f2bf(float f) {
    union { float f; u32 u; } v; v.f = f;
    u32 r = v.u + 0x7FFFu + ((v.u >> 16) & 1u);
    return (u16)(r >> 16);
}
__device__ __forceinline__ u32 pack2bf(float lo, float hi) {
    return (u32)f2bf(lo) | ((u32)f2bf(hi) << 16);
}

// async 16B global -> LDS (hardware: wave-uniform base + lane*16)
__device__ __forceinline__ void gl_lds16(const u16* g, u16* l) {
    __builtin_amdgcn_global_load_lds(
        (const __attribute__((address_space(1))) void*)g,
        (__attribute__((address_space(3))) void*)l,
        16, 0, 0);
}

// ---------------------------------------------------------------------------
// Fused prep (single dispatch, block-role split):
//   blocks [0, 1024)    : Bt[o][k=d*1024+i] <- coeffs[i][o][d] (LDS transpose)
//   blocks [1024, 9216) : A[b][k=d*1024+i]  <- V_d(tanh(x[b,i]))
// ---------------------------------------------------------------------------
#define PB_TI 128
#define PB_TO 8
#define PB_J  (PB_TO * NDEG)    // 72
#define PB_LS 132               // LDS row stride (u16): 264 B, u64-aligned rows

#define NB_B   1024             // (IDIM/PB_TI) * (ODIM/PB_TO) = 8 * 128
#define NB_A   8192             // BATCH*IDIM/2 / 256

__global__ void prep_kernel(const float* __restrict__ x,
                            const float* __restrict__ c,
                            u16* __restrict__ A, u16* __restrict__ Bt) {
    __shared__ u16 lds[PB_J * PB_LS];             // 19 KB (B-blocks only)
    const int bb  = blockIdx.x;
    const int tid = threadIdx.x;

    if (bb < NB_B) {
        // ---- B transpose: 128 i x 8 o x 9 d tile ----
        const int i0 = (bb & 7) * PB_TI;
        const int o0 = (bb >> 3) * PB_TO;
        const float* src = c + (size_t)i0 * (ODIM * NDEG) + (size_t)o0 * NDEG;
#pragma unroll
        for (int t = 0; t < 36; ++t) {            // 9216 floats / 256 threads
            int f  = t * 256 + tid;
            int ii = f / PB_J;
            int j  = f - ii * PB_J;
            float v = src[(size_t)ii * (ODIM * NDEG) + j];
            lds[j * PB_LS + ii] = f2bf(v);
        }
        __syncthreads();
#pragma unroll
        for (int t = 0; t < 9; ++t) {             // 72*32 u64 stores / 256 thr
            int g   = t * 256 + tid;
            int j   = g >> 5;                     // 0..71
            int ii4 = (g & 31) << 2;
            int o   = j / NDEG;
            int d   = j - o * NDEG;
            u64 v = *(const u64*)(lds + j * PB_LS + ii4);
            *(u64*)(Bt + (size_t)(o0 + o) * KTOT + d * 1024 + i0 + ii4) = v;
        }
    } else {
        // ---- A basis: thread handles 2 consecutive i ----
        int t  = (bb - NB_B) * 256 + tid;
        int b  = t >> 9;
        int i2 = (t & 511) << 1;
        float2 xv = ((const float2*)x)[t];
        float t0 = tanhf(xv.x), t1 = tanhf(xv.y);
        u32* dst = (u32*)(A + (size_t)b * KTOT + i2);  // d-stride = 512 u32
        float a0 = 2.0f, a1 = 2.0f;
        float b0 = t0,  b1 = t1;
        dst[0]   = pack2bf(2.0f, 2.0f);
        dst[512] = pack2bf(t0, t1);
#pragma unroll
        for (int d = 2; d < NDEG; ++d) {
            float n0 = t0 * b0 + a0;
            float n1 = t1 * b1 + a1;
            dst[(size_t)d * 512] = pack2bf(n0, n1);
            a0 = b0; b0 = n0; a1 = b1; b1 = n1;
        }
    }
}

// ---------------------------------------------------------------------------
// GEMM: P[z][m][n] = A[m][k] * Bt[n][k] over k half, 128x128 tile, BK=64,
// 4 waves of 64x64.  XCD-aware swizzle (id%8 -> XCD heuristic): each XCD
// owns a 1024x1024 output patch at half-K -> per-XCD compulsory fetch
// 9.4 MB A + 9.4 MB B; total 151 MB vs 311 MB measured unswizzled.
// LDS: [row][8 chunks of 16B], physical chunk = c ^ (row&7)
// -> global_load_lds staging + conflict-free ds_read_b128 frag reads.
// ---------------------------------------------------------------------------
__global__ __launch_bounds__(256, 2)
void gemm_kernel(const u16* __restrict__ A, const u16* __restrict__ B,
                 float* __restrict__ P) {
    __shared__ __align__(16) u16 ldsA[BM * BKK];  // 16 KB
    __shared__ __align__(16) u16 ldsB[BN * BKK];  // 16 KB

    const int tid  = threadIdx.x;
    const int lane = tid & 63;
    const int wave = tid >> 6;
    const int quad = lane >> 4;
    const int l15  = lane & 15;
    const int wm   = wave & 1;
    const int wn   = wave >> 1;

    // swizzle: xcd = id&7 gets (z = xcd>>2, bm_hi = xcd&3); loc = id>>3
    const int bid = blockIdx.x;                   // 0..511
    const int xcd = bid & 7;
    const int loc = bid >> 3;                     // 0..63
    const int z   = xcd >> 2;
    const int bm  = ((xcd & 3) << 3) | (loc >> 3);
    const int bn  = loc & 7;
    const int kStart = z * (KTOT / 2);
    float* C = P + (size_t)z * BATCH * ODIM;

    const u16* ga[4]; const u16* gb[4];
    u16* la[4]; u16* lb[4];
#pragma unroll
    for (int t = 0; t < 4; ++t) {
        int s  = t * 256 + tid;                   // 16B slot in tile, 0..1023
        int r  = s >> 3;                          // tile row 0..127
        int sc = (s & 7) ^ (r & 7);               // source k-chunk (XOR swizzle)
        ga[t] = A + (size_t)(bm * BM + r) * KTOT + kStart + sc * 8;
        gb[t] = B + (size_t)(bn * BN + r) * KTOT + kStart + sc * 8;
        la[t] = ldsA + s * 8;
        lb[t] = ldsB + s * 8;
    }

    f32x4 acc[4][4];
#pragma unroll
    for (int mt = 0; mt < 4; ++mt)
#pragma unroll
        for (int nt = 0; nt < 4; ++nt)
            acc[mt][nt] = (f32x4){0.f, 0.f, 0.f, 0.f};

    const int nIter = (KTOT / 2) / BKK;           // 72
    for (int it = 0; it < nIter; ++it) {
#pragma unroll
        for (int t = 0; t < 4; ++t) gl_lds16(ga[t], la[t]);
#pragma unroll
        for (int t = 0; t < 4; ++t) gl_lds16(gb[t], lb[t]);
        __syncthreads();

#pragma unroll
        for (int kk = 0; kk < 2; ++kk) {
            short8_t af[4], bfg[4];
#pragma unroll
            for (int mt = 0; mt < 4; ++mt) {
                int row = wm * 64 + mt * 16 + l15;
                int pc  = (kk * 4 + quad) ^ (row & 7);
                af[mt] = *(const short8_t*)(ldsA + (row * 8 + pc) * 8);
            }
#pragma unroll
            for (int nt = 0; nt < 4; ++nt) {
                int row = wn * 64 + nt * 16 + l15;
                int pc  = (kk * 4 + quad) ^ (row & 7);
                bfg[nt] = *(const short8_t*)(ldsB + (row * 8 + pc) * 8);
            }
#pragma unroll
            for (int mt = 0; mt < 4; ++mt)
#pragma unroll
                for (int nt = 0; nt < 4; ++nt)
                    acc[mt][nt] = __builtin_amdgcn_mfma_f32_16x16x32_bf16(
                        af[mt], bfg[nt], acc[mt][nt], 0, 0, 0);
        }
        __syncthreads();

#pragma unroll
        for (int t = 0; t < 4; ++t) { ga[t] += BKK; gb[t] += BKK; }
    }

    // epilogue: C/D layout col = lane&15, row = quad*4 + reg  [m89-verified]
#pragma unroll
    for (int mt = 0; mt < 4; ++mt) {
#pragma unroll
        for (int nt = 0; nt < 4; ++nt) {
            int row0 = bm * BM + wm * 64 + mt * 16 + quad * 4;
            int col  = bn * BN + wn * 64 + nt * 16 + l15;
#pragma unroll
            for (int r = 0; r < 4; ++r)
                C[(size_t)(row0 + r) * ODIM + col] = acc[mt][nt][r];
        }
    }
}

// out = P[0] + P[1]  (split-K reduction), float4 vectorized
__global__ void reduce_kernel(const float* __restrict__ P, float* __restrict__ out) {
    int t = blockIdx.x * 256 + threadIdx.x;       // over BATCH*ODIM/4
    f32x4 a = ((const f32x4*)P)[t];
    f32x4 b = ((const f32x4*)(P + (size_t)BATCH * ODIM))[t];
    ((f32x4*)out)[t] = a + b;
}

extern "C" void kernel_launch(void* const* d_in, const int* in_sizes, int n_in,
                              void* d_out, int out_size, void* d_ws, size_t ws_size,
                              hipStream_t stream) {
    const float* x      = (const float*)d_in[0];   // [4096,1024] f32
    const float* coeffs = (const float*)d_in[1];   // [1024,1024,9] f32
    float* out = (float*)d_out;                    // [4096,1024] f32

    u16* A  = (u16*)d_ws;                          // 75.5 MB
    u16* Bt = A + (size_t)BATCH * KTOT;            // 18.9 MB
    float* P = (float*)(Bt + (size_t)ODIM * KTOT); // 33.6 MB split-K partials

    prep_kernel<<<NB_B + NB_A, 256, 0, stream>>>(x, coeffs, A, Bt);
    gemm_kernel<<<512, 256, 0, stream>>>(A, Bt, P);
    reduce_kernel<<<BATCH * ODIM / 1024, 256, 0, stream>>>(P, out);
}